// Round 2
// baseline (366.720 us; speedup 1.0000x reference)
//
#include <hip/hip_runtime.h>

// GRU: B=8192, T=1024, I=3, H=4, fp32.
// R2: 2 independent batch chains per lane (ILP to hide dependency latency,
// since only 512 waves of parallelism exist and each SIMD holds <=1 wave).
// 1 block = 1 wave = 16 batch-slots x 4 hidden units x 2 chains = 32 batches.
// Weights pre-scaled by -log2(e) (r,z) and 2*log2(e) (n) so activations are
// rcp(1+exp2(arg)) with no extra muls on the critical path.

#define TC 32
#define XS_STRIDE 99   // per-batch-row stride for x_s (96 data + 3 pad)
#define OS_STRIDE 132  // per-batch-row stride for out_s (128 data + 4 pad)

template<int CTRL>
__device__ __forceinline__ float dpp_rot(float v) {
    int i = __builtin_bit_cast(int, v);
    int r = __builtin_amdgcn_mov_dpp(i, CTRL, 0xf, 0xf, true);
    return __builtin_bit_cast(float, r);
}

__device__ __forceinline__ float vrcp(float x)  { return __builtin_amdgcn_rcpf(x); }
__device__ __forceinline__ float vexp2(float x) { return __builtin_amdgcn_exp2f(x); }

__global__ __launch_bounds__(64) void gru_kernel(
    const float* __restrict__ x,     // [B, T, 3]
    const float* __restrict__ w_ih,  // [12, 3]
    const float* __restrict__ w_hh,  // [12, 4]
    const float* __restrict__ b_ih,  // [12]
    const float* __restrict__ b_hh,  // [12]
    float* __restrict__ out)         // [B*T*4] then h_n [B*4]
{
    __shared__ float x_s[32 * XS_STRIDE];    // 12.7 KB
    __shared__ float out_s[32 * OS_STRIDE];  // 16.9 KB

    const int lane = threadIdx.x;
    const int q    = lane >> 2;      // batch-slot within block (0..15)
    const int j    = lane & 3;       // hidden unit (0..3)
    const int b0   = blockIdx.x * 32;

    const float NL2E = -1.4426950408889634f;  // -log2(e): r,z gates
    const float P2   =  2.8853900817779268f;  // 2*log2(e): n gate

    // ---- per-lane constants, pre-scaled ----
    float wir[3], wiz[3], win[3];
    #pragma unroll
    for (int k = 0; k < 3; ++k) {
        wir[k] = NL2E * w_ih[j * 3 + k];
        wiz[k] = NL2E * w_ih[(4 + j) * 3 + k];
        win[k] = P2   * w_ih[(8 + j) * 3 + k];
    }
    // w_hh rows permuted so index m multiplies h_{(j+m)&3} (DPP rotate order)
    float whr[4], whz[4], whn[4];
    #pragma unroll
    for (int m = 0; m < 4; ++m) {
        int k = (j + m) & 3;
        whr[m] = NL2E * w_hh[j * 4 + k];
        whz[m] = NL2E * w_hh[(4 + j) * 4 + k];
        whn[m] = P2   * w_hh[(8 + j) * 4 + k];
    }
    const float br   = NL2E * (b_ih[j]     + b_hh[j]);
    const float bz   = NL2E * (b_ih[4 + j] + b_hh[4 + j]);
    const float bin  = P2   * b_ih[8 + j];
    const float bhn  = P2   * b_hh[8 + j];

    float h[2] = {0.0f, 0.0f};       // chain 0: batch b0+q; chain 1: batch b0+16+q

    // ---- x chunk prefetch: 32 batches x 96 floats = 768 float4, 12/lane ----
    float4 xr[12];
    #pragma unroll
    for (int u = 0; u < 12; ++u) {
        int f  = u * 64 + lane;
        int bb = f / 24;                 // 24 float4 per batch row
        int q4 = f - bb * 24;
        xr[u] = *(const float4*)(x + (long long)(b0 + bb) * 3072 + q4 * 4);
    }

    for (int c = 0; c < 32; ++c) {
        // stage prefetched regs -> LDS
        #pragma unroll
        for (int u = 0; u < 12; ++u) {
            int f  = u * 64 + lane;
            int bb = f / 24;
            int q4 = f - bb * 24;
            float* p = &x_s[bb * XS_STRIDE + q4 * 4];
            p[0] = xr[u].x; p[1] = xr[u].y; p[2] = xr[u].z; p[3] = xr[u].w;
        }
        __syncthreads();   // x_s ready; also fences last chunk's out_s flush

        // next chunk's global loads (latency covered by 32 steps of compute)
        if (c < 31) {
            int t0 = (c + 1) * TC;
            #pragma unroll
            for (int u = 0; u < 12; ++u) {
                int f  = u * 64 + lane;
                int bb = f / 24;
                int q4 = f - bb * 24;
                xr[u] = *(const float4*)(x + (long long)(b0 + bb) * 3072 + t0 * 3 + q4 * 4);
            }
        }

        // ---- 32 recurrence steps, 2 chains interleaved ----
        const float* xsA = &x_s[q * XS_STRIDE];
        const float* xsB = &x_s[(q + 16) * XS_STRIDE];
        float*       osA = &out_s[q * OS_STRIDE];
        float*       osB = &out_s[(q + 16) * OS_STRIDE];
        #pragma unroll 8
        for (int t = 0; t < TC; ++t) {
            float x0[2], x1[2], x2[2];
            x0[0] = xsA[t * 3 + 0]; x1[0] = xsA[t * 3 + 1]; x2[0] = xsA[t * 3 + 2];
            x0[1] = xsB[t * 3 + 0]; x1[1] = xsB[t * 3 + 1]; x2[1] = xsB[t * 3 + 2];
            #pragma unroll
            for (int p = 0; p < 2; ++p) {
                float sr = fmaf(wir[0], x0[p], fmaf(wir[1], x1[p], fmaf(wir[2], x2[p], br)));
                float sz = fmaf(wiz[0], x0[p], fmaf(wiz[1], x1[p], fmaf(wiz[2], x2[p], bz)));
                float sn = fmaf(win[0], x0[p], fmaf(win[1], x1[p], fmaf(win[2], x2[p], bin)));

                float h1 = dpp_rot<0x39>(h[p]);   // quad_perm [1,2,3,0]
                float h2 = dpp_rot<0x4E>(h[p]);   // quad_perm [2,3,0,1]
                float h3 = dpp_rot<0x93>(h[p]);   // quad_perm [3,0,1,2]

                float gr = fmaf(whr[0], h[p], fmaf(whr[1], h1, fmaf(whr[2], h2, whr[3] * h3)));
                float gz = fmaf(whz[0], h[p], fmaf(whz[1], h1, fmaf(whz[2], h2, whz[3] * h3)));
                float gn = fmaf(whn[0], h[p], fmaf(whn[1], h1, fmaf(whn[2], h2,
                                 fmaf(whn[3], h3, bhn))));   // bhn folded into chain init

                // r,z: args pre-scaled by -log2e  => sigmoid = rcp(1+exp2(arg))
                float r = vrcp(1.0f + vexp2(sr + gr));
                float z = vrcp(1.0f + vexp2(sz + gz));
                // n: arg pre-scaled by 2*log2e => tanh = 1 - 2*rcp(1+exp2(arg))
                float an = fmaf(r, gn, sn);
                float n  = fmaf(-2.0f, vrcp(1.0f + vexp2(an)), 1.0f);

                h[p] = fmaf(z, h[p] - n, n);      // (1-z)*n + z*h

                (p == 0 ? osA : osB)[t * 4 + j] = h[p];
            }
        }
        __syncthreads();   // out_s complete; x_s reads done before overwrite

        // ---- flush out chunk: 32 batches x 128 floats = 1024 float4, 16/lane ----
        int t0 = c * TC;
        #pragma unroll
        for (int u = 0; u < 16; ++u) {
            int f  = u * 64 + lane;
            int bb = f >> 5;                 // 32 float4 per batch row
            int qq = f & 31;
            float4 v = *(const float4*)&out_s[bb * OS_STRIDE + qq * 4];
            *(float4*)(out + (long long)(b0 + bb) * 4096 + t0 * 4 + qq * 4) = v;
        }
    }

    // ---- h_n tail: out[B*T*H + b*4 + j] ----
    out[33554432LL + (long long)(b0 + q) * 4 + j]      = h[0];
    out[33554432LL + (long long)(b0 + 16 + q) * 4 + j] = h[1];
}

extern "C" void kernel_launch(void* const* d_in, const int* in_sizes, int n_in,
                              void* d_out, int out_size, void* d_ws, size_t ws_size,
                              hipStream_t stream) {
    const float* x    = (const float*)d_in[0];
    const float* w_ih = (const float*)d_in[1];
    const float* w_hh = (const float*)d_in[2];
    const float* b_ih = (const float*)d_in[3];
    const float* b_hh = (const float*)d_in[4];
    float* out = (float*)d_out;

    dim3 grid(256), block(64);   // 256 blocks x 32 batches = 8192
    gru_kernel<<<grid, block, 0, stream>>>(x, w_ih, w_hh, b_ih, b_hh, out);
}

// Round 3
// 269.316 us; speedup vs baseline: 1.3617x; 1.3617x over previous
//
#include <hip/hip_runtime.h>

// GRU: B=8192, T=1024, I=3, H=4, fp32.
// R3: producer/consumer wave split. 512 blocks x 128 threads (2 waves).
//   wave 0 (recurrence): 16 batches x 4 units, h-chain only. Reads gi from
//     LDS, DPP quad-rotates for h exchange, writes h to LDS.
//   wave 1 (helper): loads x, computes gi = x*w_ih^T + b (non-recurrent),
//     flushes out. Double-buffered, 1 barrier per 16-step chunk.
// All 1024 waves -> one per SIMD, every SIMD occupied.
// Weights pre-scaled (-log2e for r,z; 2log2e for n) => act = rcp(1+exp2(a)).

#define TC 16
#define GI_TS 192          // gi stride per t: 16 batches * 12
#define OS_STRIDE 68       // out_s row: TC*4 + 4 pad (2-way max on h writes)

template<int CTRL>
__device__ __forceinline__ float dpp_rot(float v) {
    int i = __builtin_bit_cast(int, v);
    int r = __builtin_amdgcn_mov_dpp(i, CTRL, 0xf, 0xf, true);
    return __builtin_bit_cast(float, r);
}
__device__ __forceinline__ float vrcp(float x)  { return __builtin_amdgcn_rcpf(x); }
__device__ __forceinline__ float vexp2(float x) { return __builtin_amdgcn_exp2f(x); }

__global__ __launch_bounds__(128) void gru_kernel(
    const float* __restrict__ x,     // [B, T, 3]
    const float* __restrict__ w_ih,  // [12, 3]
    const float* __restrict__ w_hh,  // [12, 4]
    const float* __restrict__ b_ih,  // [12]
    const float* __restrict__ b_hh,  // [12]
    float* __restrict__ out)         // [B*T*4] then h_n [B*4]
{
    __shared__ float gi_s[2][TC * GI_TS];       // 24.0 KB
    __shared__ float out_s[2][16 * OS_STRIDE];  //  8.5 KB

    const int tid = threadIdx.x;
    const int b0  = blockIdx.x * 16;

    const float NL2E = -1.4426950408889634f;  // -log2(e)
    const float P2   =  2.8853900817779268f;  //  2*log2(e)

    if (tid < 64) {
        // ================= recurrence wave =================
        const int q = tid >> 2;   // batch slot 0..15
        const int j = tid & 3;    // hidden unit

        // w_hh rows permuted so index m multiplies h_{(j+m)&3} (DPP order)
        float whr[4], whz[4], whn[4];
        #pragma unroll
        for (int m = 0; m < 4; ++m) {
            int k = (j + m) & 3;
            whr[m] = NL2E * w_hh[j * 4 + k];
            whz[m] = NL2E * w_hh[(4 + j) * 4 + k];
            whn[m] = P2   * w_hh[(8 + j) * 4 + k];
        }
        const float bhn = P2 * b_hh[8 + j];

        float h = 0.0f;
        __syncthreads();   // gi chunk 0 ready

        for (int c = 0; c < 64; ++c) {
            const float* gb = &gi_s[c & 1][q * 12 + j];
            float*       os = &out_s[c & 1][q * OS_STRIDE];

            // stage the whole chunk's gi into regs (bulk ds_reads, latency
            // amortized, none on the h-chain)
            float sr[TC], sz[TC], sn[TC];
            #pragma unroll
            for (int t = 0; t < TC; ++t) {
                sr[t] = gb[t * GI_TS];
                sz[t] = gb[t * GI_TS + 4];
                sn[t] = gb[t * GI_TS + 8];
            }

            #pragma unroll
            for (int t = 0; t < TC; ++t) {
                float h1 = dpp_rot<0x39>(h);
                float h2 = dpp_rot<0x4E>(h);
                float h3 = dpp_rot<0x93>(h);
                // depth-3 trees
                float gr = fmaf(whr[0], h, whr[1] * h1) + fmaf(whr[2], h2, whr[3] * h3);
                float gz = fmaf(whz[0], h, whz[1] * h1) + fmaf(whz[2], h2, whz[3] * h3);
                float gn = fmaf(whn[0], h, whn[1] * h1) + fmaf(whn[2], h2, fmaf(whn[3], h3, bhn));

                float r = vrcp(1.0f + vexp2(sr[t] + gr));   // sigmoid (pre-scaled)
                float z = vrcp(1.0f + vexp2(sz[t] + gz));
                // off-chain prep so only one fma follows the final rcp:
                float omz   = 1.0f - z;
                float szh   = fmaf(z, h, omz);    // z*h + (1-z)
                float m2omz = -2.0f * omz;
                // n-path: u = 1/(1+e^{2a}); h' = omz*(1-2u)+z*h = fma(m2omz,u,szh)
                float u = vrcp(1.0f + vexp2(fmaf(r, gn, sn[t])));
                h = fmaf(m2omz, u, szh);

                os[t * 4 + j] = h;
            }
            __syncthreads();
        }
        // h_n tail
        out[33554432LL + (long long)(b0 + q) * 4 + j] = h;

    } else {
        // ================= helper wave =================
        const int hl = tid - 64;
        const int bb = hl >> 2;   // batch slot 0..15
        const int s  = hl & 3;    // t-slice 0..3

        // all 12 w_ih rows + fused biases (wave-uniform -> scalar regs)
        float wr[4][3], wz[4][3], wn[4][3];
        float cbr[4], cbz[4], cbn[4];
        #pragma unroll
        for (int jj = 0; jj < 4; ++jj) {
            #pragma unroll
            for (int k = 0; k < 3; ++k) {
                wr[jj][k] = NL2E * w_ih[jj * 3 + k];
                wz[jj][k] = NL2E * w_ih[(4 + jj) * 3 + k];
                wn[jj][k] = P2   * w_ih[(8 + jj) * 3 + k];
            }
            cbr[jj] = NL2E * (b_ih[jj]     + b_hh[jj]);
            cbz[jj] = NL2E * (b_ih[4 + jj] + b_hh[4 + jj]);
            cbn[jj] = P2   * b_ih[8 + jj];
        }

        const long long xbase = (long long)(b0 + bb) * 3072;

        // gi compute for chunk cc into buf
        auto compute_gi = [&](int cc, float* buf) {
            #pragma unroll
            for (int k = 0; k < 4; ++k) {
                int tl = k * 4 + s;                       // 0..15
                const float* xp = x + xbase + (long long)(cc * TC + tl) * 3;
                float x0 = xp[0], x1 = xp[1], x2 = xp[2];
                float* gp = &buf[tl * GI_TS + bb * 12];
                #pragma unroll
                for (int jj = 0; jj < 4; ++jj) {
                    gp[jj]     = fmaf(wr[jj][0], x0, fmaf(wr[jj][1], x1, fmaf(wr[jj][2], x2, cbr[jj])));
                    gp[4 + jj] = fmaf(wz[jj][0], x0, fmaf(wz[jj][1], x1, fmaf(wz[jj][2], x2, cbz[jj])));
                    gp[8 + jj] = fmaf(wn[jj][0], x0, fmaf(wn[jj][1], x1, fmaf(wn[jj][2], x2, cbn[jj])));
                }
            }
        };
        // flush chunk cc from buf to global (64 floats per batch row)
        auto flush_out = [&](int cc, const float* buf) {
            #pragma unroll
            for (int u = 0; u < 4; ++u) {
                int f   = u * 64 + hl;
                int bbf = f >> 4;
                int idx = f & 15;
                float4 v = *(const float4*)&buf[bbf * OS_STRIDE + idx * 4];
                *(float4*)(out + (long long)(b0 + bbf) * 4096 + cc * 64 + idx * 4) = v;
            }
        };

        compute_gi(0, gi_s[0]);
        __syncthreads();   // release chunk 0

        for (int c = 0; c < 64; ++c) {
            if (c < 63) compute_gi(c + 1, gi_s[(c + 1) & 1]);
            if (c > 0)  flush_out(c - 1, out_s[(c - 1) & 1]);
            __syncthreads();
        }
        flush_out(63, out_s[1]);
    }
}

extern "C" void kernel_launch(void* const* d_in, const int* in_sizes, int n_in,
                              void* d_out, int out_size, void* d_ws, size_t ws_size,
                              hipStream_t stream) {
    const float* x    = (const float*)d_in[0];
    const float* w_ih = (const float*)d_in[1];
    const float* w_hh = (const float*)d_in[2];
    const float* b_ih = (const float*)d_in[3];
    const float* b_hh = (const float*)d_in[4];
    float* out = (float*)d_out;

    dim3 grid(512), block(128);   // 512 blocks x 16 batches = 8192; 2 waves/block
    gru_kernel<<<grid, block, 0, stream>>>(x, w_ih, w_hh, b_ih, b_hh, out);
}